// Round 9
// baseline (94.130 us; speedup 1.0000x reference)
//
#include <hip/hip_runtime.h>
#include <stdint.h>

typedef unsigned long long u64;
typedef uint32_t u32;
typedef unsigned char u8;

#define B_ 4
#define N_ 300000
#define C_ 5
#define GX_ 512
#define GY_ 512
#define GZ_ 1
#define GTOT_ (GX_*GY_*GZ_)   // 262144 voxels per batch
#define NW_ (GTOT_/64)        // 4096 occupancy words per batch
#define MAXV_ 30000
#define MAXP_ 20
#define ROWS_ (B_*MAXV_)      // 120000
#define OUT0_ELEMS_ (C_*MAXP_*ROWS_)  // 12,000,000 f32 elements

__device__ __forceinline__ int voxel_lin(float x, float y, float z) {
    // Matches the precomputed reference (XLA CPU): divide-by-constant lowered
    // to multiply-by-reciprocal; 1/0.2f rounds to exactly 5.0f, 1/8 exact.
    // Verified empirically in round 5 (absmax 9.8e-4, pass).
    float qx = (x + 51.2f) * 5.0f;
    float qy = (y + 51.2f) * 5.0f;
    float qz = (z + 5.0f) * 0.125f;
    int cx = (int)floorf(qx);
    int cy = (int)floorf(qy);
    int cz = (int)floorf(qz);
    if (cx < 0 || cx >= GX_ || cy < 0 || cy >= GY_ || cz < 0 || cz >= GZ_) return -1;
    return (cz * GY_ + cy) * GX_ + cx;
}

// Pass 0: zero the occupancy flags. 65536 uint4 stores over 1 MB.
__global__ void k_init(uint4* __restrict__ occF4) {
    int i = blockIdx.x * blockDim.x + threadIdx.x;  // 0..65535
    occF4[i] = make_uint4(0u, 0u, 0u, 0u);
}

// Pass 1: occupancy byte-flags (idempotent plain stores) + lin cache so
// k_scatter doesn't re-read the 24 MB point array or recompute voxel_lin.
__global__ void k_mark(const float* __restrict__ pts, u8* __restrict__ occF,
                       int* __restrict__ linb) {
    int i = blockIdx.x * blockDim.x + threadIdx.x;
    int b = blockIdx.y;
    if (i >= N_) return;
    const float* p = pts + ((size_t)b * N_ + i) * C_;
    int lin = voxel_lin(p[0], p[1], p[2]);
    linb[(size_t)b * N_ + i] = lin;
    if (lin >= 0) occF[(size_t)b * GTOT_ + lin] = (u8)1;
}

// Pass 2 (fused scan+fill): build u64 masks + exclusive word offsets from the
// byte flags, record nOcc[b], then walk each thread's own 4 masks writing the
// slot->voxel map and zeroing cnt2[slot] (replaces the separate k_fill pass;
// offsets are monotone so off>=MAXV lets a thread break early).
__global__ __launch_bounds__(1024) void k_scan(const u8* __restrict__ occF,
                                               u64* __restrict__ occ,
                                               u32* __restrict__ wordOff,
                                               u32* __restrict__ voxOf,
                                               u32* __restrict__ cnt2,
                                               u32* __restrict__ nOcc) {
    int b = blockIdx.x;
    int t = threadIdx.x;
    const u64* of = (const u64*)(occF + (size_t)b * GTOT_);
    int base = t * 4;
    u64 msk[4];
    u32 c[4];
    #pragma unroll
    for (int w = 0; w < 4; ++w) {
        const u64* ch = of + (size_t)(base + w) * 8;
        u64 m = 0;
        #pragma unroll
        for (int k = 0; k < 8; ++k) {
            u64 v = ch[k] & 0x0101010101010101ull;
            m |= ((v * 0x0102040810204080ull) >> 56) << (8 * k);
        }
        occ[(size_t)b * NW_ + base + w] = m;
        msk[w] = m;
        c[w] = (u32)__popcll(m);
    }
    __shared__ u32 sh[1024];
    sh[t] = c[0] + c[1] + c[2] + c[3];
    __syncthreads();
    for (int off = 1; off < 1024; off <<= 1) {
        u32 v = (t >= off) ? sh[t - off] : 0u;
        __syncthreads();
        sh[t] += v;
        __syncthreads();
    }
    u32 excl = (t > 0) ? sh[t - 1] : 0u;
    u32 wo[4];
    wo[0] = excl;
    wo[1] = excl + c[0];
    wo[2] = excl + c[0] + c[1];
    wo[3] = excl + c[0] + c[1] + c[2];
    u32* wop = wordOff + (size_t)b * NW_ + base;
    wop[0] = wo[0]; wop[1] = wo[1]; wop[2] = wo[2]; wop[3] = wo[3];
    if (t == 1023) nOcc[b] = sh[1023];
    // fused fill: only threads whose words land below the MAXV cutoff do work
    #pragma unroll
    for (int w = 0; w < 4; ++w) {
        u32 off = wo[w];
        if (off >= MAXV_) break;           // monotone -> later words also out
        u64 m = msk[w];
        int vbase = (base + w) << 6;
        while (m) {
            int bit = (int)__ffsll((unsigned long long)m) - 1;
            m &= m - 1;
            if (off >= MAXV_) break;
            voxOf[b * MAXV_ + off] = (u32)(vbase + bit);
            cnt2[b * MAXV_ + off] = 0u;
            ++off;
        }
    }
}

// Pass 3: scatter point indices into their voxel slot (<=20 kept; order fixed
// in k_out). Reads the cached lin (4.8 MB) instead of the 24 MB point array.
__global__ void k_scatter(const int* __restrict__ linb, const u64* __restrict__ occ,
                          const u32* __restrict__ wordOff,
                          u32* __restrict__ cnt2, u32* __restrict__ idxbuf) {
    int i = blockIdx.x * blockDim.x + threadIdx.x;
    int b = blockIdx.y;
    if (i >= N_) return;
    int lin = linb[(size_t)b * N_ + i];
    if (lin < 0) return;
    int w = lin >> 6, bit = lin & 63;
    u32 baseOff = wordOff[(size_t)b * NW_ + w];
    if (baseOff >= MAXV_) return;          // ~83% of points exit here
    u64 m = occ[(size_t)b * NW_ + w];
    u32 slot = baseOff + (u32)__popcll(m & ((1ull << bit) - 1ull));
    if (slot >= MAXV_) return;
    u32 r = atomicAdd(&cnt2[b * MAXV_ + slot], 1u);
    if (r < MAXP_) idxbuf[((size_t)b * MAXV_ + slot) * MAXP_ + r] = (u32)i;
}

// Pass 4: one thread per output row -> sort indices (stable order), write f32 outputs
__global__ void k_out(const float* __restrict__ pts, const float* __restrict__ nr,
                      const u32* __restrict__ voxOf, const u32* __restrict__ cnt2,
                      const u32* __restrict__ idxbuf, const u32* __restrict__ nOcc,
                      float* __restrict__ out0, float* __restrict__ out1) {
    int row = blockIdx.x * blockDim.x + threadIdx.x;
    if (row >= ROWS_) return;
    int b = row / MAXV_;
    int local = row - b * MAXV_;
    u32 nv = nOcc[b];
    bool valid = (u32)local < (nv < MAXV_ ? nv : (u32)MAXV_);
    u32 lin = 0;
    int n = 0;
    u32 idxs[MAXP_];
    if (valid) {
        lin = voxOf[row];
        n = (int)min(cnt2[row], (u32)MAXP_);
        for (int r = 0; r < n; ++r) idxs[r] = idxbuf[(size_t)row * MAXP_ + r];
        // insertion sort ascending -> reference's stable (original index) order
        for (int a = 1; a < n; ++a) {
            u32 key = idxs[a];
            int j = a - 1;
            while (j >= 0 && idxs[j] > key) { idxs[j + 1] = idxs[j]; --j; }
            idxs[j + 1] = key;
        }
    }
    // coors_batch row: [b, z, y, x] as float values (d_out is f32)
    float4 cr;
    cr.x = (float)b;
    if (valid) {
        int x = lin & (GX_ - 1);
        int y = (lin >> 9) & (GY_ - 1);
        int z = (int)(lin >> 18);
        cr.y = (float)z; cr.z = (float)y; cr.w = (float)x;
    } else {
        cr.y = -1.0f; cr.z = -1.0f; cr.w = -1.0f;
    }
    *(float4*)(out1 + (size_t)row * 4) = cr;
    // normalization params (dims 0..2 only)
    float s0 = nr[0], s1 = nr[1], s2 = nr[2];
    float d0 = nr[3] - nr[0], d1 = nr[4] - nr[1], d2 = nr[5] - nr[2];
    for (int p = 0; p < MAXP_; ++p) {
        float f0 = 0.f, f1 = 0.f, f2 = 0.f, f3 = 0.f, f4 = 0.f;
        if (p < n) {
            const float* pp = pts + ((size_t)b * N_ + idxs[p]) * C_;
            f0 = (pp[0] - s0) / d0;
            f1 = (pp[1] - s1) / d1;
            f2 = (pp[2] - s2) / d2;
            f3 = pp[3];
            f4 = pp[4];
        }
        // out0 layout: [1, C, MAXP, ROWS] -> ((c*MAXP)+p)*ROWS + row (coalesced across rows)
        out0[(0 * MAXP_ + p) * ROWS_ + row] = f0;
        out0[(1 * MAXP_ + p) * ROWS_ + row] = f1;
        out0[(2 * MAXP_ + p) * ROWS_ + row] = f2;
        out0[(3 * MAXP_ + p) * ROWS_ + row] = f3;
        out0[(4 * MAXP_ + p) * ROWS_ + row] = f4;
    }
}

extern "C" void kernel_launch(void* const* d_in, const int* in_sizes, int n_in,
                              void* d_out, int out_size, void* d_ws, size_t ws_size,
                              hipStream_t stream) {
    const float* pts = (const float*)d_in[0];
    const float* nr  = (const float*)d_in[1];
    float* out0 = (float*)d_out;
    float* out1 = out0 + (size_t)OUT0_ELEMS_;

    uint8_t* ws = (uint8_t*)d_ws;
    // workspace layout (bytes), total 15,556,624 (ws is ~256 MiB per the
    // harness's 0xAA poison fill observed in round 8)
    u64* occ     = (u64*)(ws + 0);            // 4*4096*8    = 131,072
    u32* wordOff = (u32*)(ws + 131072);       // 4*4096*4    =  65,536
    u32* voxOf   = (u32*)(ws + 196608);       // 120000*4    = 480,000
    u32* cnt2    = (u32*)(ws + 676608);       // 120000*4    = 480,000
    u32* idxbuf  = (u32*)(ws + 1156608);      // 120000*20*4 = 9,600,000
    int* linb    = (int*)(ws + 10756608);     // 4*300000*4  = 4,800,000
    u32* nOcc    = (u32*)(ws + 15556608);     // 4*4 = 16
    // occF (4*262144 = 1,048,576 bytes) aliases the head of idxbuf:
    // occF is dead after k_scan; idxbuf is first written in k_scatter.
    u8*  occF    = (u8*)(ws + 1156608);

    dim3 gP((N_ + 255) / 256, B_);
    k_init   <<<(B_ * GTOT_ / 16 + 255) / 256, 256, 0, stream>>>((uint4*)occF);
    k_mark   <<<gP, 256, 0, stream>>>(pts, occF, linb);
    k_scan   <<<B_, 1024, 0, stream>>>(occF, occ, wordOff, voxOf, cnt2, nOcc);
    k_scatter<<<gP, 256, 0, stream>>>(linb, occ, wordOff, cnt2, idxbuf);
    k_out    <<<(ROWS_ + 255) / 256, 256, 0, stream>>>(pts, nr, voxOf, cnt2, idxbuf, nOcc, out0, out1);
}

// Round 10
// 58.947 us; speedup vs baseline: 1.5969x; 1.5969x over previous
//
#include <hip/hip_runtime.h>
#include <stdint.h>

typedef unsigned long long u64;
typedef uint32_t u32;
typedef unsigned char u8;

#define B_ 4
#define N_ 300000
#define C_ 5
#define GX_ 512
#define GY_ 512
#define GZ_ 1
#define GTOT_ (GX_*GY_*GZ_)   // 262144 voxels per batch
#define NW_ (GTOT_/64)        // 4096 occupancy words per batch
#define MAXV_ 30000
#define MAXP_ 20
#define ROWS_ (B_*MAXV_)      // 120000
#define OUT0_ELEMS_ (C_*MAXP_*ROWS_)  // 12,000,000 f32 elements

__device__ __forceinline__ int voxel_lin(float x, float y, float z) {
    // Matches the precomputed reference (XLA CPU): divide-by-constant lowered
    // to multiply-by-reciprocal; 1/0.2f rounds to exactly 5.0f, 1/8 exact.
    // Verified empirically in round 5 (absmax 9.8e-4, pass).
    float qx = (x + 51.2f) * 5.0f;
    float qy = (y + 51.2f) * 5.0f;
    float qz = (z + 5.0f) * 0.125f;
    int cx = (int)floorf(qx);
    int cy = (int)floorf(qy);
    int cz = (int)floorf(qz);
    if (cx < 0 || cx >= GX_ || cy < 0 || cy >= GY_ || cz < 0 || cz >= GZ_) return -1;
    return (cz * GY_ + cy) * GX_ + cx;
}

// Pass 0: zero the occupancy flags. 65536 uint4 stores over 1 MB.
__global__ void k_init(uint4* __restrict__ occF4) {
    int i = blockIdx.x * blockDim.x + threadIdx.x;  // 0..65535
    occF4[i] = make_uint4(0u, 0u, 0u, 0u);
}

// Pass 1: occupancy byte-flags (idempotent plain stores) + lin cache so
// k_scatter doesn't re-read the 24 MB point array or recompute voxel_lin.
__global__ void k_mark(const float* __restrict__ pts, u8* __restrict__ occF,
                       int* __restrict__ linb) {
    int i = blockIdx.x * blockDim.x + threadIdx.x;
    int b = blockIdx.y;
    if (i >= N_) return;
    const float* p = pts + ((size_t)b * N_ + i) * C_;
    int lin = voxel_lin(p[0], p[1], p[2]);
    linb[(size_t)b * N_ + i] = lin;
    if (lin >= 0) occF[(size_t)b * GTOT_ + lin] = (u8)1;
}

// Pass 2a (WIDE): one thread per voxel; wave ballot builds the u64 occupancy
// word for free; lane 0 writes the word and its popcount. 4096 blocks.
__global__ void k_maskcnt(const u8* __restrict__ occF, u64* __restrict__ occ,
                          u32* __restrict__ wordPop) {
    int i = blockIdx.x * blockDim.x + threadIdx.x;  // voxel id
    int b = blockIdx.y;
    u8 f = occF[(size_t)b * GTOT_ + i];
    u64 m = __ballot(f != 0);
    if ((threadIdx.x & 63) == 0) {
        int w = i >> 6;
        occ[(size_t)b * NW_ + w] = m;
        wordPop[(size_t)b * NW_ + w] = (u32)__popcll(m);
    }
}

// Pass 2b (tiny): exclusive scan of word popcounts; 64 KB total read.
__global__ __launch_bounds__(1024) void k_scan2(const u32* __restrict__ wordPop,
                                                u32* __restrict__ wordOff,
                                                u32* __restrict__ nOcc) {
    int b = blockIdx.x;
    int t = threadIdx.x;
    const uint4* wp = (const uint4*)(wordPop + (size_t)b * NW_);
    uint4 v = wp[t];
    __shared__ u32 sh[1024];
    sh[t] = v.x + v.y + v.z + v.w;
    __syncthreads();
    for (int off = 1; off < 1024; off <<= 1) {
        u32 u = (t >= off) ? sh[t - off] : 0u;
        __syncthreads();
        sh[t] += u;
        __syncthreads();
    }
    u32 excl = (t > 0) ? sh[t - 1] : 0u;
    u32* wo = wordOff + (size_t)b * NW_ + t * 4;
    wo[0] = excl;
    wo[1] = excl + v.x;
    wo[2] = excl + v.x + v.y;
    wo[3] = excl + v.x + v.y + v.z;
    if (t == 1023) nOcc[b] = sh[1023];
}

// Pass 3 (WIDE): slot -> voxel map, one thread per voxel; zeroes cnt2[slot]
// (exactly one thread per kept slot; stream order beats k_scatter's atomics).
__global__ void k_fill(const u64* __restrict__ occ, const u32* __restrict__ wordOff,
                       u32* __restrict__ voxOf, u32* __restrict__ cnt2) {
    int i = blockIdx.x * blockDim.x + threadIdx.x;  // 0..GTOT_-1
    int b = blockIdx.y;
    int w = i >> 6, bit = i & 63;
    u64 m = occ[(size_t)b * NW_ + w];
    if (!((m >> bit) & 1ull)) return;
    u32 slot = wordOff[(size_t)b * NW_ + w] + (u32)__popcll(m & ((1ull << bit) - 1ull));
    if (slot < MAXV_) {
        voxOf[b * MAXV_ + slot] = (u32)i;
        cnt2[b * MAXV_ + slot] = 0u;
    }
}

// Pass 4: scatter point indices into their voxel slot (<=20 kept; order fixed
// in k_out). Reads the cached lin (4.8 MB) instead of the 24 MB point array.
__global__ void k_scatter(const int* __restrict__ linb, const u64* __restrict__ occ,
                          const u32* __restrict__ wordOff,
                          u32* __restrict__ cnt2, u32* __restrict__ idxbuf) {
    int i = blockIdx.x * blockDim.x + threadIdx.x;
    int b = blockIdx.y;
    if (i >= N_) return;
    int lin = linb[(size_t)b * N_ + i];
    if (lin < 0) return;
    int w = lin >> 6, bit = lin & 63;
    u32 baseOff = wordOff[(size_t)b * NW_ + w];
    if (baseOff >= MAXV_) return;          // ~83% of points exit here
    u64 m = occ[(size_t)b * NW_ + w];
    u32 slot = baseOff + (u32)__popcll(m & ((1ull << bit) - 1ull));
    if (slot >= MAXV_) return;
    u32 r = atomicAdd(&cnt2[b * MAXV_ + slot], 1u);
    if (r < MAXP_) idxbuf[((size_t)b * MAXV_ + slot) * MAXP_ + r] = (u32)i;
}

// Pass 5: one thread per output row -> sort indices (stable order), write f32 outputs
__global__ void k_out(const float* __restrict__ pts, const float* __restrict__ nr,
                      const u32* __restrict__ voxOf, const u32* __restrict__ cnt2,
                      const u32* __restrict__ idxbuf, const u32* __restrict__ nOcc,
                      float* __restrict__ out0, float* __restrict__ out1) {
    int row = blockIdx.x * blockDim.x + threadIdx.x;
    if (row >= ROWS_) return;
    int b = row / MAXV_;
    int local = row - b * MAXV_;
    u32 nv = nOcc[b];
    bool valid = (u32)local < (nv < MAXV_ ? nv : (u32)MAXV_);
    u32 lin = 0;
    int n = 0;
    u32 idxs[MAXP_];
    if (valid) {
        lin = voxOf[row];
        n = (int)min(cnt2[row], (u32)MAXP_);
        for (int r = 0; r < n; ++r) idxs[r] = idxbuf[(size_t)row * MAXP_ + r];
        // insertion sort ascending -> reference's stable (original index) order
        for (int a = 1; a < n; ++a) {
            u32 key = idxs[a];
            int j = a - 1;
            while (j >= 0 && idxs[j] > key) { idxs[j + 1] = idxs[j]; --j; }
            idxs[j + 1] = key;
        }
    }
    // coors_batch row: [b, z, y, x] as float values (d_out is f32)
    float4 cr;
    cr.x = (float)b;
    if (valid) {
        int x = lin & (GX_ - 1);
        int y = (lin >> 9) & (GY_ - 1);
        int z = (int)(lin >> 18);
        cr.y = (float)z; cr.z = (float)y; cr.w = (float)x;
    } else {
        cr.y = -1.0f; cr.z = -1.0f; cr.w = -1.0f;
    }
    *(float4*)(out1 + (size_t)row * 4) = cr;
    // normalization params (dims 0..2 only)
    float s0 = nr[0], s1 = nr[1], s2 = nr[2];
    float d0 = nr[3] - nr[0], d1 = nr[4] - nr[1], d2 = nr[5] - nr[2];
    for (int p = 0; p < MAXP_; ++p) {
        float f0 = 0.f, f1 = 0.f, f2 = 0.f, f3 = 0.f, f4 = 0.f;
        if (p < n) {
            const float* pp = pts + ((size_t)b * N_ + idxs[p]) * C_;
            f0 = (pp[0] - s0) / d0;
            f1 = (pp[1] - s1) / d1;
            f2 = (pp[2] - s2) / d2;
            f3 = pp[3];
            f4 = pp[4];
        }
        // out0 layout: [1, C, MAXP, ROWS] -> ((c*MAXP)+p)*ROWS + row (coalesced across rows)
        out0[(0 * MAXP_ + p) * ROWS_ + row] = f0;
        out0[(1 * MAXP_ + p) * ROWS_ + row] = f1;
        out0[(2 * MAXP_ + p) * ROWS_ + row] = f2;
        out0[(3 * MAXP_ + p) * ROWS_ + row] = f3;
        out0[(4 * MAXP_ + p) * ROWS_ + row] = f4;
    }
}

extern "C" void kernel_launch(void* const* d_in, const int* in_sizes, int n_in,
                              void* d_out, int out_size, void* d_ws, size_t ws_size,
                              hipStream_t stream) {
    const float* pts = (const float*)d_in[0];
    const float* nr  = (const float*)d_in[1];
    float* out0 = (float*)d_out;
    float* out1 = out0 + (size_t)OUT0_ELEMS_;

    uint8_t* ws = (uint8_t*)d_ws;
    // workspace layout (bytes), total 15,622,160 (ws is ~256 MiB per the
    // harness's 0xAA poison fill observed in round 8)
    u64* occ     = (u64*)(ws + 0);            // 4*4096*8    = 131,072
    u32* wordOff = (u32*)(ws + 131072);       // 4*4096*4    =  65,536
    u32* voxOf   = (u32*)(ws + 196608);       // 120000*4    = 480,000
    u32* cnt2    = (u32*)(ws + 676608);       // 120000*4    = 480,000
    u32* idxbuf  = (u32*)(ws + 1156608);      // 120000*20*4 = 9,600,000
    int* linb    = (int*)(ws + 10756608);     // 4*300000*4  = 4,800,000
    u32* wordPop = (u32*)(ws + 15556608);     // 4*4096*4    =  65,536
    u32* nOcc    = (u32*)(ws + 15622144);     // 4*4 = 16
    // occF (4*262144 = 1,048,576 bytes) aliases the head of idxbuf:
    // occF is dead after k_maskcnt; idxbuf is first written in k_scatter.
    u8*  occF    = (u8*)(ws + 1156608);

    dim3 gP((N_ + 255) / 256, B_);
    dim3 gV(GTOT_ / 256, B_);
    k_init   <<<(B_ * GTOT_ / 16 + 255) / 256, 256, 0, stream>>>((uint4*)occF);
    k_mark   <<<gP, 256, 0, stream>>>(pts, occF, linb);
    k_maskcnt<<<gV, 256, 0, stream>>>(occF, occ, wordPop);
    k_scan2  <<<B_, 1024, 0, stream>>>(wordPop, wordOff, nOcc);
    k_fill   <<<gV, 256, 0, stream>>>(occ, wordOff, voxOf, cnt2);
    k_scatter<<<gP, 256, 0, stream>>>(linb, occ, wordOff, cnt2, idxbuf);
    k_out    <<<(ROWS_ + 255) / 256, 256, 0, stream>>>(pts, nr, voxOf, cnt2, idxbuf, nOcc, out0, out1);
}

// Round 11
// 56.348 us; speedup vs baseline: 1.6705x; 1.0461x over previous
//
#include <hip/hip_runtime.h>
#include <stdint.h>

typedef unsigned long long u64;
typedef uint32_t u32;
typedef unsigned char u8;

#define B_ 4
#define N_ 300000
#define C_ 5
#define GX_ 512
#define GY_ 512
#define GZ_ 1
#define GTOT_ (GX_*GY_*GZ_)   // 262144 voxels per batch
#define NW_ (GTOT_/64)        // 4096 occupancy words per batch
#define MAXV_ 30000
#define MAXP_ 20
#define ROWS_ (B_*MAXV_)      // 120000
#define OUT0_ELEMS_ (C_*MAXP_*ROWS_)  // 12,000,000 f32 elements

// init sizes in uint4 units
#define OCCF_Q_ (B_*GTOT_/16)   // 65536
#define CNT2_Q_ (ROWS_/4)       // 30000
#define INIT_Q_ (OCCF_Q_ + CNT2_Q_)  // 95536

__device__ __forceinline__ int voxel_lin(float x, float y, float z) {
    // Matches the precomputed reference (XLA CPU): divide-by-constant lowered
    // to multiply-by-reciprocal; 1/0.2f rounds to exactly 5.0f, 1/8 exact.
    // Verified empirically in round 5 (absmax 9.8e-4, pass).
    float qx = (x + 51.2f) * 5.0f;
    float qy = (y + 51.2f) * 5.0f;
    float qz = (z + 5.0f) * 0.125f;
    int cx = (int)floorf(qx);
    int cy = (int)floorf(qy);
    int cz = (int)floorf(qz);
    if (cx < 0 || cx >= GX_ || cy < 0 || cy >= GY_ || cz < 0 || cz >= GZ_) return -1;
    return (cz * GY_ + cy) * GX_ + cx;
}

// Pass 0: zero occF (1 MB) and cnt2 (480 KB) in one wide fill kernel.
__global__ void k_init(uint4* __restrict__ occF4, uint4* __restrict__ cnt2q) {
    int i = blockIdx.x * blockDim.x + threadIdx.x;
    if (i < OCCF_Q_) occF4[i] = make_uint4(0u, 0u, 0u, 0u);
    else if (i < INIT_Q_) cnt2q[i - OCCF_Q_] = make_uint4(0u, 0u, 0u, 0u);
}

// Pass 1: occupancy byte-flags (idempotent plain stores) + lin cache so
// k_scatter doesn't re-read the 24 MB point array or recompute voxel_lin.
__global__ void k_mark(const float* __restrict__ pts, u8* __restrict__ occF,
                       int* __restrict__ linb) {
    int i = blockIdx.x * blockDim.x + threadIdx.x;
    int b = blockIdx.y;
    if (i >= N_) return;
    const float* p = pts + ((size_t)b * N_ + i) * C_;
    int lin = voxel_lin(p[0], p[1], p[2]);
    linb[(size_t)b * N_ + i] = lin;
    if (lin >= 0) occF[(size_t)b * GTOT_ + lin] = (u8)1;
}

// Pass 2a (WIDE): one thread per voxel; wave ballot builds the u64 occupancy
// word for free; lane 0 writes the word and its popcount.
__global__ void k_maskcnt(const u8* __restrict__ occF, u64* __restrict__ occ,
                          u32* __restrict__ wordPop) {
    int i = blockIdx.x * blockDim.x + threadIdx.x;  // voxel id
    int b = blockIdx.y;
    u8 f = occF[(size_t)b * GTOT_ + i];
    u64 m = __ballot(f != 0);
    if ((threadIdx.x & 63) == 0) {
        int w = i >> 6;
        occ[(size_t)b * NW_ + w] = m;
        wordPop[(size_t)b * NW_ + w] = (u32)__popcll(m);
    }
}

// Pass 2b (tiny): exclusive scan of word popcounts; 64 KB total read.
__global__ __launch_bounds__(1024) void k_scan2(const u32* __restrict__ wordPop,
                                                u32* __restrict__ wordOff,
                                                u32* __restrict__ nOcc) {
    int b = blockIdx.x;
    int t = threadIdx.x;
    const uint4* wp = (const uint4*)(wordPop + (size_t)b * NW_);
    uint4 v = wp[t];
    __shared__ u32 sh[1024];
    sh[t] = v.x + v.y + v.z + v.w;
    __syncthreads();
    for (int off = 1; off < 1024; off <<= 1) {
        u32 u = (t >= off) ? sh[t - off] : 0u;
        __syncthreads();
        sh[t] += u;
        __syncthreads();
    }
    u32 excl = (t > 0) ? sh[t - 1] : 0u;
    u32* wo = wordOff + (size_t)b * NW_ + t * 4;
    wo[0] = excl;
    wo[1] = excl + v.x;
    wo[2] = excl + v.x + v.y;
    wo[3] = excl + v.x + v.y + v.z;
    if (t == 1023) nOcc[b] = sh[1023];
}

// Pass 3: scatter point indices into their voxel slot (<=20 kept; order fixed
// in k_out). The atomic winner (r==0) also records the slot's voxel id —
// replaces the former per-voxel k_fill pass (every valid slot has >=1 point,
// and all its points carry the same lin, so exactly one race-free write).
__global__ void k_scatter(const int* __restrict__ linb, const u64* __restrict__ occ,
                          const u32* __restrict__ wordOff,
                          u32* __restrict__ cnt2, u32* __restrict__ idxbuf,
                          u32* __restrict__ voxOf) {
    int i = blockIdx.x * blockDim.x + threadIdx.x;
    int b = blockIdx.y;
    if (i >= N_) return;
    int lin = linb[(size_t)b * N_ + i];
    if (lin < 0) return;
    int w = lin >> 6, bit = lin & 63;
    u32 baseOff = wordOff[(size_t)b * NW_ + w];
    if (baseOff >= MAXV_) return;          // ~83% of points exit here
    u64 m = occ[(size_t)b * NW_ + w];
    u32 slot = baseOff + (u32)__popcll(m & ((1ull << bit) - 1ull));
    if (slot >= MAXV_) return;
    u32 r = atomicAdd(&cnt2[b * MAXV_ + slot], 1u);
    if (r == 0) voxOf[b * MAXV_ + slot] = (u32)lin;
    if (r < MAXP_) idxbuf[((size_t)b * MAXV_ + slot) * MAXP_ + r] = (u32)i;
}

// Pass 4: one thread per output row -> sort indices (stable order), write f32 outputs
__global__ void k_out(const float* __restrict__ pts, const float* __restrict__ nr,
                      const u32* __restrict__ voxOf, const u32* __restrict__ cnt2,
                      const u32* __restrict__ idxbuf, const u32* __restrict__ nOcc,
                      float* __restrict__ out0, float* __restrict__ out1) {
    int row = blockIdx.x * blockDim.x + threadIdx.x;
    if (row >= ROWS_) return;
    int b = row / MAXV_;
    int local = row - b * MAXV_;
    u32 nv = nOcc[b];
    bool valid = (u32)local < (nv < MAXV_ ? nv : (u32)MAXV_);
    u32 lin = 0;
    int n = 0;
    u32 idxs[MAXP_];
    if (valid) {
        lin = voxOf[row];
        n = (int)min(cnt2[row], (u32)MAXP_);
        for (int r = 0; r < n; ++r) idxs[r] = idxbuf[(size_t)row * MAXP_ + r];
        // insertion sort ascending -> reference's stable (original index) order
        for (int a = 1; a < n; ++a) {
            u32 key = idxs[a];
            int j = a - 1;
            while (j >= 0 && idxs[j] > key) { idxs[j + 1] = idxs[j]; --j; }
            idxs[j + 1] = key;
        }
    }
    // coors_batch row: [b, z, y, x] as float values (d_out is f32)
    float4 cr;
    cr.x = (float)b;
    if (valid) {
        int x = lin & (GX_ - 1);
        int y = (lin >> 9) & (GY_ - 1);
        int z = (int)(lin >> 18);
        cr.y = (float)z; cr.z = (float)y; cr.w = (float)x;
    } else {
        cr.y = -1.0f; cr.z = -1.0f; cr.w = -1.0f;
    }
    *(float4*)(out1 + (size_t)row * 4) = cr;
    // normalization params (dims 0..2 only)
    float s0 = nr[0], s1 = nr[1], s2 = nr[2];
    float d0 = nr[3] - nr[0], d1 = nr[4] - nr[1], d2 = nr[5] - nr[2];
    for (int p = 0; p < MAXP_; ++p) {
        float f0 = 0.f, f1 = 0.f, f2 = 0.f, f3 = 0.f, f4 = 0.f;
        if (p < n) {
            const float* pp = pts + ((size_t)b * N_ + idxs[p]) * C_;
            f0 = (pp[0] - s0) / d0;
            f1 = (pp[1] - s1) / d1;
            f2 = (pp[2] - s2) / d2;
            f3 = pp[3];
            f4 = pp[4];
        }
        // out0 layout: [1, C, MAXP, ROWS] -> ((c*MAXP)+p)*ROWS + row (coalesced across rows)
        out0[(0 * MAXP_ + p) * ROWS_ + row] = f0;
        out0[(1 * MAXP_ + p) * ROWS_ + row] = f1;
        out0[(2 * MAXP_ + p) * ROWS_ + row] = f2;
        out0[(3 * MAXP_ + p) * ROWS_ + row] = f3;
        out0[(4 * MAXP_ + p) * ROWS_ + row] = f4;
    }
}

extern "C" void kernel_launch(void* const* d_in, const int* in_sizes, int n_in,
                              void* d_out, int out_size, void* d_ws, size_t ws_size,
                              hipStream_t stream) {
    const float* pts = (const float*)d_in[0];
    const float* nr  = (const float*)d_in[1];
    float* out0 = (float*)d_out;
    float* out1 = out0 + (size_t)OUT0_ELEMS_;

    uint8_t* ws = (uint8_t*)d_ws;
    // workspace layout (bytes), total 15,622,160 (ws is ~256 MiB per the
    // harness's 0xAA poison fill observed in round 8)
    u64* occ     = (u64*)(ws + 0);            // 4*4096*8    = 131,072
    u32* wordOff = (u32*)(ws + 131072);       // 4*4096*4    =  65,536
    u32* voxOf   = (u32*)(ws + 196608);       // 120000*4    = 480,000
    u32* cnt2    = (u32*)(ws + 676608);       // 120000*4    = 480,000
    u32* idxbuf  = (u32*)(ws + 1156608);      // 120000*20*4 = 9,600,000
    int* linb    = (int*)(ws + 10756608);     // 4*300000*4  = 4,800,000
    u32* wordPop = (u32*)(ws + 15556608);     // 4*4096*4    =  65,536
    u32* nOcc    = (u32*)(ws + 15622144);     // 4*4 = 16
    // occF (4*262144 = 1,048,576 bytes) aliases the head of idxbuf:
    // occF is dead after k_maskcnt; idxbuf is first written in k_scatter.
    u8*  occF    = (u8*)(ws + 1156608);

    dim3 gP((N_ + 255) / 256, B_);
    dim3 gV(GTOT_ / 256, B_);
    k_init   <<<(INIT_Q_ + 255) / 256, 256, 0, stream>>>((uint4*)occF, (uint4*)cnt2);
    k_mark   <<<gP, 256, 0, stream>>>(pts, occF, linb);
    k_maskcnt<<<gV, 256, 0, stream>>>(occF, occ, wordPop);
    k_scan2  <<<B_, 1024, 0, stream>>>(wordPop, wordOff, nOcc);
    k_scatter<<<gP, 256, 0, stream>>>(linb, occ, wordOff, cnt2, idxbuf, voxOf);
    k_out    <<<(ROWS_ + 255) / 256, 256, 0, stream>>>(pts, nr, voxOf, cnt2, idxbuf, nOcc, out0, out1);
}